// Round 7
// baseline (206.534 us; speedup 1.0000x reference)
//
#include <hip/hip_runtime.h>
#include <math.h>

#define Hd 264
#define Wd 480
#define W4 (Wd / 4)            // 120
#define HW (Hd * Wd)
#define NB 16
#define NC 9
#define KK 50
#define NPLANE (NB * NC)
#define NDET (NB * KK)
#define CAP 6912
#define STRIP 33
#define NCHUNK (Hd / STRIP)    // 8
#define SLAB_CAP 2048
#define SCAP 1024
#define NK (NC * KK)           // 450
#define PI_F 3.14159274101257324f
#define TWO_PI_F 6.28318548202514648f

__device__ const float DIMM[9][3] = {
    {3.99331126f, 1.54370861f, 1.64175497f},
    {0.295f, 1.6f, 0.3175f},
    {1.34645161f, 1.55322581f, 0.3883871f},
    {2.503f, 1.72f, 1.077f},
    {9.1775f, 2.95f, 2.3425f},
    {10.3655102f, 3.31632653f, 2.45469388f},
    {6.016911083f, 3.412001685f, 2.2783185f},
    {4.824963f, 2.046904f, 1.78939f},
    {8.8040879f, 2.916193f, 2.07649252f}};

__device__ const float ACENT[4] = {0.0f, 1.57079637050628662f, 3.14159274101257324f, -1.57079637050628662f};

__device__ __forceinline__ float4 max4(float4 a, float4 b) {
    return make_float4(fmaxf(a.x, b.x), fmaxf(a.y, b.y), fmaxf(a.z, b.z), fmaxf(a.w, b.w));
}

// Kernel 1 (UNCHANGED from R6): streaming 5x5 NMS, register ring + tiny LDS row.
__global__ __launch_bounds__(128) void nms_stream(const float* __restrict__ cls,
                                                  unsigned long long* __restrict__ slabs,
                                                  int* __restrict__ slabCnt) {
    __shared__ float rowbuf[2][488];
    __shared__ unsigned long long sbuf[SLAB_CAP];
    __shared__ int scnt;

    const int plane = blockIdx.y;
    const int chunk = blockIdx.x;
    const int lane = threadIdx.x;
    const bool act = lane < W4;
    const float4* heat4 = (const float4*)(cls + (size_t)plane * HW);
    const int gy0 = chunk * STRIP;

    if (lane < 2) { rowbuf[0][lane] = -INFINITY; rowbuf[1][lane] = -INFINITY; }
    if (lane < 6) { rowbuf[0][482 + lane] = -INFINITY; rowbuf[1][482 + lane] = -INFINITY; }
    if (lane == 0) scnt = 0;

    const float4 NEG = make_float4(-INFINITY, -INFINITY, -INFINITY, -INFINITY);
    float4 r0 = NEG, r1 = NEG, r2 = NEG, r3 = NEG, r4 = NEG;

    float4 nxt;
    {
        const int ry = gy0 - 2;
        nxt = (act && ry >= 0) ? heat4[ry * W4 + lane] : NEG;
    }

    for (int t = 0; t < STRIP + 4; ++t) {
        const float4 cur = nxt;
        if (t < STRIP + 3) {
            const int ry = gy0 - 1 + t;
            nxt = (act && ry >= 0 && ry < Hd) ? heat4[ry * W4 + lane] : NEG;
        }
        r0 = r1; r1 = r2; r2 = r3; r3 = r4; r4 = cur;
        if (t < 4) continue;

        const int buf = t & 1;
        if (act) {
            const float4 vm = max4(max4(r0, r1), max4(max4(r2, r3), r4));
            *(float2*)&rowbuf[buf][2 + 4 * lane] = make_float2(vm.x, vm.y);
            *(float2*)&rowbuf[buf][4 + 4 * lane] = make_float2(vm.z, vm.w);
        }
        __syncthreads();
        if (act) {
            const float4 a = *(const float4*)&rowbuf[buf][4 * lane];
            const float4 b = *(const float4*)&rowbuf[buf][4 * lane + 4];
            const float c = fmaxf(fmaxf(a.z, a.w), b.x);
            const float h0 = fmaxf(fmaxf(a.x, a.y), c);
            const float h1 = fmaxf(fmaxf(a.y, b.y), c);
            const float h2 = fmaxf(fmaxf(b.y, b.z), c);
            const float h3 = fmaxf(fmaxf(fmaxf(a.w, b.x), fmaxf(b.y, b.z)), b.w);
            const int gy = gy0 + t - 4;
            const unsigned int base = (unsigned int)(gy * Wd + 4 * lane);
            if (r2.x == h0) {
                const int p = atomicAdd(&scnt, 1);
                if (p < SLAB_CAP) sbuf[p] = ((unsigned long long)__float_as_uint(r2.x) << 32) |
                                            (unsigned long long)(0xFFFFFFFFu - base);
            }
            if (r2.y == h1) {
                const int p = atomicAdd(&scnt, 1);
                if (p < SLAB_CAP) sbuf[p] = ((unsigned long long)__float_as_uint(r2.y) << 32) |
                                            (unsigned long long)(0xFFFFFFFFu - (base + 1));
            }
            if (r2.z == h2) {
                const int p = atomicAdd(&scnt, 1);
                if (p < SLAB_CAP) sbuf[p] = ((unsigned long long)__float_as_uint(r2.z) << 32) |
                                            (unsigned long long)(0xFFFFFFFFu - (base + 2));
            }
            if (r2.w == h3) {
                const int p = atomicAdd(&scnt, 1);
                if (p < SLAB_CAP) sbuf[p] = ((unsigned long long)__float_as_uint(r2.w) << 32) |
                                            (unsigned long long)(0xFFFFFFFFu - (base + 3));
            }
        }
    }
    __syncthreads();
    const int n = min(scnt, SLAB_CAP);
    const int slab = plane * NCHUNK + chunk;
    unsigned long long* dst = slabs + (size_t)slab * SLAB_CAP;
    for (int j = lane; j < n; j += 128) dst[j] = sbuf[j];
    if (lane == 0) slabCnt[slab] = n;
}

// Kernel 2 (UNCHANGED from R6): per-plane exact top-50 via two-level radix rank-select.
__global__ __launch_bounds__(256) void plane_topk(const unsigned long long* __restrict__ slabs,
                                                  const int* __restrict__ slabCnt,
                                                  unsigned long long* __restrict__ planeKeys) {
    __shared__ unsigned long long cand[CAP];
    __shared__ int hist[4096];
    __shared__ int csum[256];
    __shared__ unsigned long long S[SCAP];
    __shared__ int soff[NCHUNK + 1];
    __shared__ int s_b1, s_acc, s_b2, s_scnt, s_need2;
    __shared__ unsigned long long wmax[4];
    __shared__ unsigned long long sprev;

    const int plane = blockIdx.x;
    const int tid = threadIdx.x;

    if (tid < NCHUNK) soff[tid + 1] = min(slabCnt[plane * NCHUNK + tid], SLAB_CAP);
    if (tid == 0) { soff[0] = 0; s_scnt = 0; }
    for (int j = tid; j < 4096; j += 256) hist[j] = 0;
    __syncthreads();
    if (tid == 0) {
        for (int c = 1; c <= NCHUNK; ++c) soff[c] += soff[c - 1];
    }
    __syncthreads();
    const int n = min(soff[NCHUNK], CAP);

    for (int j = tid; j < n; j += 256) {
        int lo = 0, hi = NCHUNK;
        while (hi - lo > 1) { const int mid = (lo + hi) >> 1; if (soff[mid] <= j) lo = mid; else hi = mid; }
        cand[j] = slabs[(size_t)(plane * NCHUNK + lo) * SLAB_CAP + (j - soff[lo])];
    }
    __syncthreads();

    for (int j = tid; j < n; j += 256) atomicAdd(&hist[(unsigned int)(cand[j] >> 52)], 1);
    __syncthreads();
    {
        int s = 0;
#pragma unroll 4
        for (int q = 0; q < 16; ++q) s += hist[tid * 16 + q];
        csum[tid] = s;
    }
    __syncthreads();
    if (tid == 0) {
        int acc = 0, b1 = 0;
        int t = 255;
        for (; t >= 0; --t) { if (acc + csum[t] >= KK) break; acc += csum[t]; }
        if (t < 0) { b1 = 0; } else {
            int b = t * 16 + 15;
            for (; b > t * 16; --b) { if (acc + hist[b] >= KK) break; acc += hist[b]; }
            b1 = b;
        }
        s_b1 = b1;
        s_acc = acc;
        s_need2 = (acc + hist[b1] > SCAP) ? 1 : 0;
    }
    __syncthreads();
    const int b1 = s_b1;
    const int need2 = s_need2;
    int b2 = 0;

    if (need2) {
        for (int j = tid; j < 4096; j += 256) hist[j] = 0;
        __syncthreads();
        for (int j = tid; j < n; j += 256) {
            const unsigned long long k = cand[j];
            if ((unsigned int)(k >> 52) == (unsigned int)b1)
                atomicAdd(&hist[(unsigned int)(k >> 40) & 0xFFFu], 1);
        }
        __syncthreads();
        {
            int s = 0;
#pragma unroll 4
            for (int q = 0; q < 16; ++q) s += hist[tid * 16 + q];
            csum[tid] = s;
        }
        __syncthreads();
        if (tid == 0) {
            const int target = KK - s_acc;
            int acc2 = 0, bb = 0;
            int t = 255;
            for (; t >= 0; --t) { if (acc2 + csum[t] >= target) break; acc2 += csum[t]; }
            if (t < 0) { bb = 0; } else {
                int b = t * 16 + 15;
                for (; b > t * 16; --b) { if (acc2 + hist[b] >= target) break; acc2 += hist[b]; }
                bb = b;
            }
            s_b2 = bb;
        }
        __syncthreads();
        b2 = s_b2;
    }

    for (int j = tid; j < n; j += 256) {
        const unsigned long long k = cand[j];
        const unsigned int p1 = (unsigned int)(k >> 52);
        bool sel;
        if (!need2) sel = (p1 >= (unsigned int)b1);
        else sel = (p1 > (unsigned int)b1) ||
                   (p1 == (unsigned int)b1 && ((unsigned int)(k >> 40) & 0xFFFu) >= (unsigned int)b2);
        if (sel) {
            const int p = atomicAdd(&s_scnt, 1);
            if (p < SCAP) S[p] = k;
        }
    }
    for (int j = tid; j < KK; j += 256) planeKeys[plane * KK + j] = 0;
    __syncthreads();
    const int scnt = s_scnt;

    if (scnt <= SCAP) {
        for (int idx = tid; idx < scnt; idx += 256) {
            const unsigned long long k = S[idx];
            int r = 0;
            for (int j = 0; j < scnt; ++j) r += (S[j] > k) ? 1 : 0;
            if (r < KK) planeKeys[plane * KK + r] = k;
        }
    } else {
        unsigned long long prev = ~0ull;
        for (int it = 0; it < KK; ++it) {
            unsigned long long mk = 0;
            for (int j = tid; j < n; j += 256) {
                unsigned long long k = cand[j];
                if (k == prev) { cand[j] = 0; k = 0; }
                if (k > mk) mk = k;
            }
            for (int s = 32; s > 0; s >>= 1) {
                const unsigned long long o = __shfl_down(mk, s);
                if (o > mk) mk = o;
            }
            if ((tid & 63) == 0) wmax[tid >> 6] = mk;
            __syncthreads();
            if (tid == 0) {
                unsigned long long m = wmax[0];
                if (wmax[1] > m) m = wmax[1];
                if (wmax[2] > m) m = wmax[2];
                if (wmax[3] > m) m = wmax[3];
                planeKeys[plane * KK + it] = m;
                sprev = m;
            }
            __syncthreads();
            prev = sprev;
        }
    }
}

// Kernel 3 (NEW): single block, 1024 threads = 16 waves.
// Phase A: wave b ranks batch b's 450 keys (exact top-50, same keyed order).
// Phase B: batch-global segment-max dedup over all 800 dets.
// Phase C: per-det gather (26 scattered loads, full ILP per thread) + math + writes.
__global__ __launch_bounds__(1024) void final_all(const unsigned long long* __restrict__ planeKeys,
                                                  const float* __restrict__ regs,
                                                  const float* __restrict__ calib,
                                                  float* __restrict__ out) {
    __shared__ union {
        unsigned long long k2[NB][NK];              // 57.6 KB (phase A)
        struct { float sc[NDET]; int ind[NDET]; int cl[NDET]; } det;  // 9.6 KB (phase B/C)
    } u;

    const int tid = threadIdx.x;
    const int wb = tid >> 6;       // wave id == batch id
    const int lane = tid & 63;

    // Phase A-load: k2[b][j] = (scorebits<<32) | ~j  (class-major flat j tiebreak).
    for (int t = tid; t < NB * NK; t += 1024) {
        const int b = t / NK, j = t - (t / NK) * NK;
        const unsigned long long pk = planeKeys[b * NK + j];
        u.k2[b][j] = (pk & 0xFFFFFFFF00000000ull) | (unsigned long long)(0xFFFFFFFFu - (unsigned int)j);
    }
    __syncthreads();

    // Phase A-rank: each lane owns up to 8 keys of its wave's batch.
    unsigned long long mykey[8];
    int myidx[8], myrank[8];
#pragma unroll
    for (int q = 0; q < 8; ++q) {
        const int idx = q * 64 + lane;
        myidx[q] = idx;
        mykey[q] = (idx < NK) ? u.k2[wb][idx] : ~0ull;
        myrank[q] = 0;
    }
    for (int j = 0; j < NK; ++j) {
        const unsigned long long kj = u.k2[wb][j];   // broadcast read
#pragma unroll
        for (int q = 0; q < 8; ++q) myrank[q] += (kj > mykey[q]) ? 1 : 0;
    }
    __syncthreads();   // all ranking reads done before det.* aliases k2

    // Phase A-write: winners (rank < 50) into det arrays (LDS).
#pragma unroll
    for (int q = 0; q < 8; ++q) {
        if (myidx[q] < NK && myrank[q] < KK) {
            const int slot = wb * KK + myrank[q];
            const int f = myidx[q];
            const unsigned long long pk = planeKeys[wb * NK + f];  // L2-hot reload for index
            u.det.sc[slot] = __uint_as_float((unsigned int)(mykey[q] >> 32));
            u.det.ind[slot] = (int)(0xFFFFFFFFu - (unsigned int)(pk & 0xFFFFFFFFull));
            u.det.cl[slot] = f / KK;
        }
    }
    __syncthreads();

    if (tid >= NDET) return;
    const int i = tid;

    // Phase C-issue: start the 26 scattered HBM loads early (independent, deep ILP).
    const int ind0 = u.det.ind[i];
    const int ind = (ind0 >= 0 && ind0 < HW) ? ind0 : 0;
    const int b = i / KK;
    const float* rp = regs + (size_t)b * 46 * HW + (size_t)ind;
    float s[26];
#pragma unroll
    for (int t = 0; t < 26; ++t) {
        const int ch = (t < 6) ? t : t + 16;  // 0-5, 22-24, 25-40, 41
        s[t] = rp[(size_t)ch * HW];
    }

    // Phase B: batch-global segment-max (reference segment_max over spatial index).
    const int cls = u.det.cl[i];
    const float score = u.det.sc[i];
    const bool th = score >= 0.29f;
    const float key_i = th ? (float)cls * 10000.0f - (float)i : -INFINITY;
    float m = -INFINITY;
    for (int j = 0; j < NDET; ++j) {
        if (u.det.ind[j] == ind0 && u.det.sc[j] >= 0.29f) {
            m = fmaxf(m, (float)u.det.cl[j] * 10000.0f - (float)j);
        }
    }
    const bool valid = th && (key_i == m);

    // Phase C: per-det math.
    const float x = (float)(ind % Wd);
    const float y = (float)(ind / Wd);

    const float r0 = fmaxf(s[0], 0.0f), r1 = fmaxf(s[1], 0.0f);
    const float r2 = fmaxf(s[2], 0.0f), r3 = fmaxf(s[3], 0.0f);
    const float cx = x + s[4];
    const float cy = y + s[5];

    const float bx1 = fminf(fmaxf((cx - r0) * 4.0f, 0.0f), 1920.0f);
    const float by1 = fminf(fmaxf((cy - r1) * 4.0f, 0.0f), 1056.0f);
    const float bx2 = fminf(fmaxf((cx + r2) * 4.0f, 0.0f), 1920.0f);
    const float by2 = fminf(fmaxf((cy + r3) * 4.0f, 0.0f), 1056.0f);

    const float dim0 = expf(s[6]) * DIMM[cls][0];
    const float dim1 = expf(s[7]) * DIMM[cls][1];
    const float dim2 = expf(s[8]) * DIMM[cls][2];

    const float sig = 1.0f / (1.0f + expf(-s[25]));
    const float depth = fminf(fmaxf(1.0f / sig - 1.0f, 0.1f), 200.0f);

    const float fu = calib[0], cu = calib[2], fv = calib[5], cv = calib[6];
    const float bxo = calib[3] / -fu;
    const float byo = calib[7] / -fv;
    const float locx = (cx * 4.0f - cu) * depth / fu + bxo;
    const float locy = (cy * 4.0f - cv) * depth / fv + byo;

    float best = -INFINITY;
    int bidx = 0;
#pragma unroll
    for (int t = 0; t < 4; ++t) {
        const float l0 = s[9 + 2 * t], l1 = s[9 + 2 * t + 1];
        const float mm = fmaxf(l0, l1);
        const float p1 = expf(l1 - mm) / (expf(l0 - mm) + expf(l1 - mm));
        if (p1 > best) { best = p1; bidx = t; }
    }
    const float sel0 = s[17 + 2 * bidx], sel1 = s[17 + 2 * bidx + 1];
    float alpha = atanf(sel0 / sel1) + ACENT[bidx];
    const float ray = atanf(locx / depth);
    float roty = alpha + ray;
    if (roty > PI_F) roty -= TWO_PI_F;
    if (roty < -PI_F) roty += TWO_PI_F;
    if (alpha > PI_F) alpha -= TWO_PI_F;
    if (alpha < -PI_F) alpha += TWO_PI_F;

    float* o = out + (size_t)i * 14;
    o[0] = bx1; o[1] = by1; o[2] = bx2; o[3] = by2;
    o[4] = dim0; o[5] = dim1; o[6] = dim2;
    o[7] = depth;
    o[8] = locx; o[9] = locy; o[10] = depth;
    o[11] = roty; o[12] = alpha;
    o[13] = score;
    out[NDET * 14 + i] = valid ? 1.0f : 0.0f;
    out[NDET * 15 + i] = (float)cls;
}

extern "C" void kernel_launch(void* const* d_in, const int* in_sizes, int n_in,
                              void* d_out, int out_size, void* d_ws, size_t ws_size,
                              hipStream_t stream) {
    const float* cls = (const float*)d_in[0];
    const float* regs = (const float*)d_in[1];
    const float* calib = (const float*)d_in[2];
    float* out = (float*)d_out;
    char* ws = (char*)d_ws;

    int* slabCnt = (int*)ws;                                         // 144*8*4 B (pad 32K)
    unsigned long long* slabs = (unsigned long long*)(ws + 32768);   // 144*8*2048*8 B
    unsigned long long* planeKeys = (unsigned long long*)(ws + 32768 + 18874368);  // 144*50*8 B

    hipLaunchKernelGGL(nms_stream, dim3(NCHUNK, NPLANE), dim3(128), 0, stream, cls, slabs, slabCnt);
    hipLaunchKernelGGL(plane_topk, dim3(NPLANE), dim3(256), 0, stream, slabs, slabCnt, planeKeys);
    hipLaunchKernelGGL(final_all, dim3(1), dim3(1024), 0, stream, planeKeys, regs, calib, out);
}

// Round 8
// 84.398 us; speedup vs baseline: 2.4471x; 2.4471x over previous
//
#include <hip/hip_runtime.h>
#include <math.h>

#define Hd 264
#define Wd 480
#define W4 (Wd / 4)            // 120
#define HW (Hd * Wd)
#define NB 16
#define NC 9
#define KK 50
#define NPLANE (NB * NC)
#define NDET (NB * KK)
#define CAP 6912
#define STRIP 33
#define NCHUNK (Hd / STRIP)    // 8
#define SLAB_CAP 2048
#define SCAP 1024
#define PI_F 3.14159274101257324f
#define TWO_PI_F 6.28318548202514648f

__device__ const float DIMM[9][3] = {
    {3.99331126f, 1.54370861f, 1.64175497f},
    {0.295f, 1.6f, 0.3175f},
    {1.34645161f, 1.55322581f, 0.3883871f},
    {2.503f, 1.72f, 1.077f},
    {9.1775f, 2.95f, 2.3425f},
    {10.3655102f, 3.31632653f, 2.45469388f},
    {6.016911083f, 3.412001685f, 2.2783185f},
    {4.824963f, 2.046904f, 1.78939f},
    {8.8040879f, 2.916193f, 2.07649252f}};

__device__ const float ACENT[4] = {0.0f, 1.57079637050628662f, 3.14159274101257324f, -1.57079637050628662f};

__device__ __forceinline__ float4 max4(float4 a, float4 b) {
    return make_float4(fmaxf(a.x, b.x), fmaxf(a.y, b.y), fmaxf(a.z, b.z), fmaxf(a.w, b.w));
}

// Kernel 1 (UNCHANGED from R6): streaming 5x5 NMS, register ring + tiny LDS row.
__global__ __launch_bounds__(128) void nms_stream(const float* __restrict__ cls,
                                                  unsigned long long* __restrict__ slabs,
                                                  int* __restrict__ slabCnt) {
    __shared__ float rowbuf[2][488];
    __shared__ unsigned long long sbuf[SLAB_CAP];
    __shared__ int scnt;

    const int plane = blockIdx.y;
    const int chunk = blockIdx.x;
    const int lane = threadIdx.x;
    const bool act = lane < W4;
    const float4* heat4 = (const float4*)(cls + (size_t)plane * HW);
    const int gy0 = chunk * STRIP;

    if (lane < 2) { rowbuf[0][lane] = -INFINITY; rowbuf[1][lane] = -INFINITY; }
    if (lane < 6) { rowbuf[0][482 + lane] = -INFINITY; rowbuf[1][482 + lane] = -INFINITY; }
    if (lane == 0) scnt = 0;

    const float4 NEG = make_float4(-INFINITY, -INFINITY, -INFINITY, -INFINITY);
    float4 r0 = NEG, r1 = NEG, r2 = NEG, r3 = NEG, r4 = NEG;

    float4 nxt;
    {
        const int ry = gy0 - 2;
        nxt = (act && ry >= 0) ? heat4[ry * W4 + lane] : NEG;
    }

    for (int t = 0; t < STRIP + 4; ++t) {
        const float4 cur = nxt;
        if (t < STRIP + 3) {
            const int ry = gy0 - 1 + t;
            nxt = (act && ry >= 0 && ry < Hd) ? heat4[ry * W4 + lane] : NEG;
        }
        r0 = r1; r1 = r2; r2 = r3; r3 = r4; r4 = cur;
        if (t < 4) continue;

        const int buf = t & 1;
        if (act) {
            const float4 vm = max4(max4(r0, r1), max4(max4(r2, r3), r4));
            *(float2*)&rowbuf[buf][2 + 4 * lane] = make_float2(vm.x, vm.y);
            *(float2*)&rowbuf[buf][4 + 4 * lane] = make_float2(vm.z, vm.w);
        }
        __syncthreads();
        if (act) {
            const float4 a = *(const float4*)&rowbuf[buf][4 * lane];
            const float4 b = *(const float4*)&rowbuf[buf][4 * lane + 4];
            const float c = fmaxf(fmaxf(a.z, a.w), b.x);
            const float h0 = fmaxf(fmaxf(a.x, a.y), c);
            const float h1 = fmaxf(fmaxf(a.y, b.y), c);
            const float h2 = fmaxf(fmaxf(b.y, b.z), c);
            const float h3 = fmaxf(fmaxf(fmaxf(a.w, b.x), fmaxf(b.y, b.z)), b.w);
            const int gy = gy0 + t - 4;
            const unsigned int base = (unsigned int)(gy * Wd + 4 * lane);
            if (r2.x == h0) {
                const int p = atomicAdd(&scnt, 1);
                if (p < SLAB_CAP) sbuf[p] = ((unsigned long long)__float_as_uint(r2.x) << 32) |
                                            (unsigned long long)(0xFFFFFFFFu - base);
            }
            if (r2.y == h1) {
                const int p = atomicAdd(&scnt, 1);
                if (p < SLAB_CAP) sbuf[p] = ((unsigned long long)__float_as_uint(r2.y) << 32) |
                                            (unsigned long long)(0xFFFFFFFFu - (base + 1));
            }
            if (r2.z == h2) {
                const int p = atomicAdd(&scnt, 1);
                if (p < SLAB_CAP) sbuf[p] = ((unsigned long long)__float_as_uint(r2.z) << 32) |
                                            (unsigned long long)(0xFFFFFFFFu - (base + 2));
            }
            if (r2.w == h3) {
                const int p = atomicAdd(&scnt, 1);
                if (p < SLAB_CAP) sbuf[p] = ((unsigned long long)__float_as_uint(r2.w) << 32) |
                                            (unsigned long long)(0xFFFFFFFFu - (base + 3));
            }
        }
    }
    __syncthreads();
    const int n = min(scnt, SLAB_CAP);
    const int slab = plane * NCHUNK + chunk;
    unsigned long long* dst = slabs + (size_t)slab * SLAB_CAP;
    for (int j = lane; j < n; j += 128) dst[j] = sbuf[j];
    if (lane == 0) slabCnt[slab] = n;
}

// Kernel 2: per-plane exact top-50.
// FAST PATH (new): count keys with value >= 0.998 (wave-aggregated, no hot-bin
// atomics). If 50 <= count <= SCAP, that value-threshold set is prefix-closed in
// key order -> compact + exact rank-by-count-greater. Bit-exact.
// FALLBACK (R6 path, any-data correctness): two-level radix histogram select.
__global__ __launch_bounds__(256) void plane_topk(const unsigned long long* __restrict__ slabs,
                                                  const int* __restrict__ slabCnt,
                                                  unsigned long long* __restrict__ planeKeys) {
    __shared__ unsigned long long cand[CAP];
    __shared__ int hist[4096];
    __shared__ int csum[256];
    __shared__ unsigned long long S[SCAP];
    __shared__ int soff[NCHUNK + 1];
    __shared__ int s_b1, s_acc, s_b2, s_scnt, s_need2, s_nhi;
    __shared__ unsigned long long wmax[4];
    __shared__ unsigned long long sprev;

    const int plane = blockIdx.x;
    const int tid = threadIdx.x;

    if (tid < NCHUNK) soff[tid + 1] = min(slabCnt[plane * NCHUNK + tid], SLAB_CAP);
    if (tid == 0) { soff[0] = 0; s_scnt = 0; s_nhi = 0; }
    for (int j = tid; j < 4096; j += 256) hist[j] = 0;
    __syncthreads();
    if (tid == 0) {
        for (int c = 1; c <= NCHUNK; ++c) soff[c] += soff[c - 1];
    }
    __syncthreads();
    const int n = min(soff[NCHUNK], CAP);

    // Gather the 8 slabs via per-element binary search.
    for (int j = tid; j < n; j += 256) {
        int lo = 0, hi = NCHUNK;
        while (hi - lo > 1) { const int mid = (lo + hi) >> 1; if (soff[mid] <= j) lo = mid; else hi = mid; }
        cand[j] = slabs[(size_t)(plane * NCHUNK + lo) * SLAB_CAP + (j - soff[lo])];
    }
    __syncthreads();

    // ---- Fast path: fixed value threshold ----
    const unsigned int TB = __float_as_uint(0.998f);
    {
        int myhi = 0;
        for (int j = tid; j < n; j += 256) myhi += ((unsigned int)(cand[j] >> 32) >= TB) ? 1 : 0;
#pragma unroll
        for (int s = 32; s > 0; s >>= 1) myhi += __shfl_down(myhi, s);
        if ((tid & 63) == 0) atomicAdd(&s_nhi, myhi);
    }
    __syncthreads();
    const int nHi = s_nhi;

    if (nHi >= KK && nHi <= SCAP) {
        for (int j = tid; j < n; j += 256) {
            const unsigned long long k = cand[j];
            if ((unsigned int)(k >> 32) >= TB) {
                const int p = atomicAdd(&s_scnt, 1);  // uniform addr -> wave-aggregated
                S[p] = k;
            }
        }
        __syncthreads();
        const int sc = s_scnt;
        for (int idx = tid; idx < sc; idx += 256) {
            const unsigned long long k = S[idx];
            int r = 0;
            for (int j = 0; j < sc; ++j) r += (S[j] > k) ? 1 : 0;
            if (r < KK) planeKeys[plane * KK + r] = k;
        }
        return;
    }

    // ---- Fallback: R6 two-level radix histogram (correct for any data) ----
    for (int j = tid; j < n; j += 256) atomicAdd(&hist[(unsigned int)(cand[j] >> 52)], 1);
    __syncthreads();
    {
        int s = 0;
#pragma unroll 4
        for (int q = 0; q < 16; ++q) s += hist[tid * 16 + q];
        csum[tid] = s;
    }
    __syncthreads();
    if (tid == 0) {
        int acc = 0, b1 = 0;
        int t = 255;
        for (; t >= 0; --t) { if (acc + csum[t] >= KK) break; acc += csum[t]; }
        if (t < 0) { b1 = 0; } else {
            int b = t * 16 + 15;
            for (; b > t * 16; --b) { if (acc + hist[b] >= KK) break; acc += hist[b]; }
            b1 = b;
        }
        s_b1 = b1;
        s_acc = acc;
        s_need2 = (acc + hist[b1] > SCAP) ? 1 : 0;
    }
    __syncthreads();
    const int b1 = s_b1;
    const int need2 = s_need2;
    int b2 = 0;

    if (need2) {
        for (int j = tid; j < 4096; j += 256) hist[j] = 0;
        __syncthreads();
        for (int j = tid; j < n; j += 256) {
            const unsigned long long k = cand[j];
            if ((unsigned int)(k >> 52) == (unsigned int)b1)
                atomicAdd(&hist[(unsigned int)(k >> 40) & 0xFFFu], 1);
        }
        __syncthreads();
        {
            int s = 0;
#pragma unroll 4
            for (int q = 0; q < 16; ++q) s += hist[tid * 16 + q];
            csum[tid] = s;
        }
        __syncthreads();
        if (tid == 0) {
            const int target = KK - s_acc;
            int acc2 = 0, bb = 0;
            int t = 255;
            for (; t >= 0; --t) { if (acc2 + csum[t] >= target) break; acc2 += csum[t]; }
            if (t < 0) { bb = 0; } else {
                int b = t * 16 + 15;
                for (; b > t * 16; --b) { if (acc2 + hist[b] >= target) break; acc2 += hist[b]; }
                bb = b;
            }
            s_b2 = bb;
        }
        __syncthreads();
        b2 = s_b2;
    }

    for (int j = tid; j < n; j += 256) {
        const unsigned long long k = cand[j];
        const unsigned int p1 = (unsigned int)(k >> 52);
        bool sel;
        if (!need2) sel = (p1 >= (unsigned int)b1);
        else sel = (p1 > (unsigned int)b1) ||
                   (p1 == (unsigned int)b1 && ((unsigned int)(k >> 40) & 0xFFFu) >= (unsigned int)b2);
        if (sel) {
            const int p = atomicAdd(&s_scnt, 1);
            if (p < SCAP) S[p] = k;
        }
    }
    for (int j = tid; j < KK; j += 256) planeKeys[plane * KK + j] = 0;
    __syncthreads();
    const int scnt = s_scnt;

    if (scnt <= SCAP) {
        for (int idx = tid; idx < scnt; idx += 256) {
            const unsigned long long k = S[idx];
            int r = 0;
            for (int j = 0; j < scnt; ++j) r += (S[j] > k) ? 1 : 0;
            if (r < KK) planeKeys[plane * KK + r] = k;
        }
    } else {
        unsigned long long prev = ~0ull;
        for (int it = 0; it < KK; ++it) {
            unsigned long long mk = 0;
            for (int j = tid; j < n; j += 256) {
                unsigned long long k = cand[j];
                if (k == prev) { cand[j] = 0; k = 0; }
                if (k > mk) mk = k;
            }
            for (int s = 32; s > 0; s >>= 1) {
                const unsigned long long o = __shfl_down(mk, s);
                if (o > mk) mk = o;
            }
            if ((tid & 63) == 0) wmax[tid >> 6] = mk;
            __syncthreads();
            if (tid == 0) {
                unsigned long long m = wmax[0];
                if (wmax[1] > m) m = wmax[1];
                if (wmax[2] > m) m = wmax[2];
                if (wmax[3] > m) m = wmax[3];
                planeKeys[plane * KK + it] = m;
                sprev = m;
            }
            __syncthreads();
            prev = sprev;
        }
    }
}

// Kernel 3 (R6 version): per batch — exact top-50 of 450 unique keys by direct ranking.
__global__ __launch_bounds__(256) void batch_topk(const unsigned long long* __restrict__ planeKeys,
                                                  float* __restrict__ dScore, int* __restrict__ dInd,
                                                  int* __restrict__ dCls) {
    __shared__ unsigned long long k2[NC * KK];
    __shared__ unsigned int sidx[NC * KK];

    const int b = blockIdx.x;
    const int tid = threadIdx.x;
    for (int j = tid; j < NC * KK; j += 256) {
        const unsigned long long pk = planeKeys[(b * NC + j / KK) * KK + (j % KK)];
        sidx[j] = 0xFFFFFFFFu - (unsigned int)(pk & 0xFFFFFFFFull);
        k2[j] = (pk & 0xFFFFFFFF00000000ull) | (unsigned long long)(0xFFFFFFFFu - (unsigned int)j);
    }
    __syncthreads();

    for (int idx = tid; idx < NC * KK; idx += 256) {
        const unsigned long long k = k2[idx];
        int r = 0;
        for (int j = 0; j < NC * KK; ++j) r += (k2[j] > k) ? 1 : 0;
        if (r < KK) {
            dScore[b * KK + r] = __uint_as_float((unsigned int)(k >> 32));
            dInd[b * KK + r] = (int)sidx[idx];
            dCls[b * KK + r] = idx / KK;
        }
    }
}

// Kernel 4 (R6 version): fused per-detection finalize, 800 blocks x 64.
__global__ __launch_bounds__(64) void finalize(const float* __restrict__ regs,
                                               const float* __restrict__ calib,
                                               const float* __restrict__ dScore,
                                               const int* __restrict__ dInd,
                                               const int* __restrict__ dCls,
                                               float* __restrict__ out) {
    __shared__ float s[26];
    const int i = blockIdx.x;
    const int lane = threadIdx.x;
    const int ind0 = dInd[i];
    const int ind = (ind0 >= 0 && ind0 < HW) ? ind0 : 0;
    const int b = i / KK;

    if (lane < 26) {
        const int ch = (lane < 6) ? lane : lane + 16;  // 0-5, 22-24, 25-40, 41
        s[lane] = regs[(size_t)b * 46 * HW + (size_t)ch * HW + (size_t)ind];
    }

    float m = -INFINITY;
    for (int j = lane; j < NDET; j += 64) {
        if (dInd[j] == ind0 && dScore[j] >= 0.29f) {
            m = fmaxf(m, (float)dCls[j] * 10000.0f - (float)j);
        }
    }
#pragma unroll
    for (int sft = 32; sft > 0; sft >>= 1) m = fmaxf(m, __shfl_down(m, sft));
    __syncthreads();
    if (lane != 0) return;

    const int cls = dCls[i];
    const float score = dScore[i];
    const bool th = score >= 0.29f;
    const float key_i = th ? (float)cls * 10000.0f - (float)i : -INFINITY;
    const bool valid = th && (key_i == m);

    const float x = (float)(ind % Wd);
    const float y = (float)(ind / Wd);

    const float r0 = fmaxf(s[0], 0.0f), r1 = fmaxf(s[1], 0.0f);
    const float r2 = fmaxf(s[2], 0.0f), r3 = fmaxf(s[3], 0.0f);
    const float cx = x + s[4];
    const float cy = y + s[5];

    const float bx1 = fminf(fmaxf((cx - r0) * 4.0f, 0.0f), 1920.0f);
    const float by1 = fminf(fmaxf((cy - r1) * 4.0f, 0.0f), 1056.0f);
    const float bx2 = fminf(fmaxf((cx + r2) * 4.0f, 0.0f), 1920.0f);
    const float by2 = fminf(fmaxf((cy + r3) * 4.0f, 0.0f), 1056.0f);

    const float dim0 = expf(s[6]) * DIMM[cls][0];
    const float dim1 = expf(s[7]) * DIMM[cls][1];
    const float dim2 = expf(s[8]) * DIMM[cls][2];

    const float sig = 1.0f / (1.0f + expf(-s[25]));
    const float depth = fminf(fmaxf(1.0f / sig - 1.0f, 0.1f), 200.0f);

    const float fu = calib[0], cu = calib[2], fv = calib[5], cv = calib[6];
    const float bxo = calib[3] / -fu;
    const float byo = calib[7] / -fv;
    const float locx = (cx * 4.0f - cu) * depth / fu + bxo;
    const float locy = (cy * 4.0f - cv) * depth / fv + byo;

    float best = -INFINITY;
    int bidx = 0;
#pragma unroll
    for (int t = 0; t < 4; ++t) {
        const float l0 = s[9 + 2 * t], l1 = s[9 + 2 * t + 1];
        const float mm = fmaxf(l0, l1);
        const float p1 = expf(l1 - mm) / (expf(l0 - mm) + expf(l1 - mm));
        if (p1 > best) { best = p1; bidx = t; }
    }
    const float sel0 = s[17 + 2 * bidx], sel1 = s[17 + 2 * bidx + 1];
    float alpha = atanf(sel0 / sel1) + ACENT[bidx];
    const float ray = atanf(locx / depth);
    float roty = alpha + ray;
    if (roty > PI_F) roty -= TWO_PI_F;
    if (roty < -PI_F) roty += TWO_PI_F;
    if (alpha > PI_F) alpha -= TWO_PI_F;
    if (alpha < -PI_F) alpha += TWO_PI_F;

    float* o = out + (size_t)i * 14;
    o[0] = bx1; o[1] = by1; o[2] = bx2; o[3] = by2;
    o[4] = dim0; o[5] = dim1; o[6] = dim2;
    o[7] = depth;
    o[8] = locx; o[9] = locy; o[10] = depth;
    o[11] = roty; o[12] = alpha;
    o[13] = score;
    out[NDET * 14 + i] = valid ? 1.0f : 0.0f;
    out[NDET * 15 + i] = (float)cls;
}

extern "C" void kernel_launch(void* const* d_in, const int* in_sizes, int n_in,
                              void* d_out, int out_size, void* d_ws, size_t ws_size,
                              hipStream_t stream) {
    const float* cls = (const float*)d_in[0];
    const float* regs = (const float*)d_in[1];
    const float* calib = (const float*)d_in[2];
    float* out = (float*)d_out;
    char* ws = (char*)d_ws;

    int* slabCnt = (int*)ws;                                         // 144*8*4 B (pad 32K)
    unsigned long long* slabs = (unsigned long long*)(ws + 32768);   // 144*8*2048*8 B
    char* tail = ws + 32768 + 18874368;
    unsigned long long* planeKeys = (unsigned long long*)tail;       // 144*50*8 B
    float* dScore = (float*)(tail + 57600);
    int* dInd = (int*)(tail + 60800);
    int* dCls = (int*)(tail + 64000);

    hipLaunchKernelGGL(nms_stream, dim3(NCHUNK, NPLANE), dim3(128), 0, stream, cls, slabs, slabCnt);
    hipLaunchKernelGGL(plane_topk, dim3(NPLANE), dim3(256), 0, stream, slabs, slabCnt, planeKeys);
    hipLaunchKernelGGL(batch_topk, dim3(NB), dim3(256), 0, stream, planeKeys, dScore, dInd, dCls);
    hipLaunchKernelGGL(finalize, dim3(NDET), dim3(64), 0, stream, regs, calib, dScore, dInd, dCls, out);
}